// Round 10
// baseline (50.904 us; speedup 1.0000x reference)
//
#include <hip/hip_runtime.h>
#include <hip/hip_bf16.h>

#define SEQ    2048
#define NHEAD  16
#define RPH    512          // rows per head = B*D
#define BM     128
#define BK     32
#define NTH    256

#define WSTRIDE 2184        // elems per wrev copy; 2184 % 64 == 8 (uniform slots)
#define ABUF_B  8192        // bytes per A buffer (128 rows x 32 cols bf16)
#define WCOP_E  8192        // elem offset of wcop (after the two A buffers)
#define TOT_E   (WCOP_E + 8 * WSTRIDE)   // 25664 elems = 51328 B
// wbase staging (guard 0..7, data 8..2055, zero pad 2056..2215) aliases abuf0

typedef float  f32x4  __attribute__((ext_vector_type(4)));
typedef __bf16 bf16x8 __attribute__((ext_vector_type(8)));

struct PF { float4 v0, v1, v2, v3; };

__device__ __forceinline__ unsigned f2bf(float f) {
    union { __hip_bfloat16 h; unsigned short u; } cv;
    cv.h = __float2bfloat16(f);
    return (unsigned)cv.u;
}

__device__ __forceinline__ uint4 pack8u(float4 a, float4 b) {
    union { bf16x8 v; uint4 u; } r;
    r.v[0] = (__bf16)a.x; r.v[1] = (__bf16)a.y;
    r.v[2] = (__bf16)a.z; r.v[3] = (__bf16)a.w;
    r.v[4] = (__bf16)b.x; r.v[5] = (__bf16)b.y;
    r.v[6] = (__bf16)b.z; r.v[7] = (__bf16)b.w;
    return r.u;
}

#define MFMA16(a, b, c) __builtin_amdgcn_mfma_f32_16x16x32_bf16((a), (b), (c), 0, 0, 0)

// Load this lane's 2 rows x 8 cols fp32 slice at column offset OFF from Xt.
#define LOADPF(P, OFF)                                                        \
  { const float* g_ = Xt + (OFF);                                             \
    P.v0 = *(const float4*)g_;                                                \
    P.v1 = *(const float4*)(g_ + 4);                                          \
    P.v2 = *(const float4*)(g_ + 16 * SEQ);                                   \
    P.v3 = *(const float4*)(g_ + 16 * SEQ + 4); }

// Pack+write P into the wave-private rows of buffer AB (row stride 64 B,
// bank-balanced without swizzle at BK=32).
#define WRITEA(AB, P)                                                         \
  { *(uint4*)((AB) + wb0) = pack8u(P.v0, P.v1);                               \
    *(uint4*)((AB) + wb1) = pack8u(P.v2, P.v3); }

// One K=32 chunk, ch = 4t + J (J compile-time 0..3):
//  1. write chunk ch+1 (staged regs) into the other A buffer
//  2. reload that pf set with chunk ch+3 (global, ~2-chunk distance)
//  3. 16 MFMAs: A frags from LDS, B words from circular bwc[8],
//     slot(ch, c) = (2ch - c) & 7 (all compile-time)
//  4. refill the 2 window words chunk ch+1 needs (slots 2ch+1, 2ch+2)
#define CHUNK32(J, ABC, ABN, PFN, LAST)                                       \
  {                                                                           \
    if (!(LAST) || (J) < 3) WRITEA(ABN, PFN);                                 \
    if (!(LAST) || (J) < 1) LOADPF(PFN, 32 * (J) + 96);                       \
    __builtin_amdgcn_s_setprio(1);                                            \
    bf16x8 af0 = *(const bf16x8*)((ABC) + Arow0 + kq16);                      \
    bf16x8 af1 = *(const bf16x8*)((ABC) + Arow1 + kq16);                      \
    acc[0][0] = MFMA16(af0, bwc[(2*(J)+8)&7], acc[0][0]);                     \
    acc[1][0] = MFMA16(af1, bwc[(2*(J)+8)&7], acc[1][0]);                     \
    acc[0][1] = MFMA16(af0, bwc[(2*(J)+7)&7], acc[0][1]);                     \
    acc[1][1] = MFMA16(af1, bwc[(2*(J)+7)&7], acc[1][1]);                     \
    acc[0][2] = MFMA16(af0, bwc[(2*(J)+6)&7], acc[0][2]);                     \
    acc[1][2] = MFMA16(af1, bwc[(2*(J)+6)&7], acc[1][2]);                     \
    acc[0][3] = MFMA16(af0, bwc[(2*(J)+5)&7], acc[0][3]);                     \
    acc[1][3] = MFMA16(af1, bwc[(2*(J)+5)&7], acc[1][3]);                     \
    acc[0][4] = MFMA16(af0, bwc[(2*(J)+4)&7], acc[0][4]);                     \
    acc[1][4] = MFMA16(af1, bwc[(2*(J)+4)&7], acc[1][4]);                     \
    acc[0][5] = MFMA16(af0, bwc[(2*(J)+3)&7], acc[0][5]);                     \
    acc[1][5] = MFMA16(af1, bwc[(2*(J)+3)&7], acc[1][5]);                     \
    acc[0][6] = MFMA16(af0, bwc[(2*(J)+2)&7], acc[0][6]);                     \
    acc[1][6] = MFMA16(af1, bwc[(2*(J)+2)&7], acc[1][6]);                     \
    acc[0][7] = MFMA16(af0, bwc[(2*(J)+1)&7], acc[0][7]);                     \
    acc[1][7] = MFMA16(af1, bwc[(2*(J)+1)&7], acc[1][7]);                     \
    __builtin_amdgcn_s_setprio(0);                                            \
    if (!(LAST) || (J) < 3) {                                                 \
      bwc[(2*(J)+1)&7] = *(const bf16x8*)(wp + 32*(J) + 16);                  \
      bwc[(2*(J)+2)&7] = *(const bf16x8*)(wp + 32*(J) + 32);                  \
    }                                                                         \
  }

__global__ __launch_bounds__(NTH, 3) void mixer_kernel(
    const float* __restrict__ x, const float* __restrict__ wgt,
    const float* __restrict__ bias, float* __restrict__ out)
{
    __shared__ unsigned short smem[TOT_E] __attribute__((aligned(16)));
    char* ab0 = (char*)smem;                    // A buffer 0 (even chunks)
    char* ab1 = (char*)smem + ABUF_B;           // A buffer 1 (odd chunks)
    unsigned short* wc = smem + WCOP_E;         // 8 shifted reversed-w copies

    const int tid  = threadIdx.x;
    const int lane = tid & 63;
    const int wv   = tid >> 6;

    // ---- block decode: 512 blocks, uniform 68 chunks each ----
    const int bid  = blockIdx.x;               // 0..511
    const int m    = (bid & 7) + 8 * ((bid >> 3) & 1);
    const int rt   = (bid >> 4) & 3;           // row tile 0..3
    const int pr   = bid >> 6;                 // 0..7
    const int ct_hi = 15 - pr;
    const int ct_lo = pr;

    const float* Xb = x   + (size_t)(m * RPH + rt * BM) * SEQ;
    float*       Ob = out + (size_t)(m * RPH + rt * BM) * SEQ;
    const float* wr = wgt  + m * SEQ;
    const float* br = bias + m * SEQ;

    // ---- wave-private staging map: wave wv owns rows [32*wv, 32*wv+32) ----
    const int sr2   = lane >> 2;               // 0..15
    const int sc2   = (lane & 3) * 8;          // 0..24 (fp32 col)
    const int rbw   = 32 * wv;
    const int wb0   = (rbw + sr2) * 64 + (lane & 3) * 16;
    const int wb1   = wb0 + 1024;              // +16 rows
    const float* Xp = Xb + (size_t)(rbw + sr2) * SEQ + sc2;

    // ---- issue chunk-0/1 prefetch immediately (hides under prologue) ----
    PF pf0, pf1;
    { const float* Xt = Xp; LOADPF(pf0, 0); LOADPF(pf1, 32); }

    // ---- phase 1: reversed bf16 weights into abuf-alias ----
    {
        const int t8 = tid * 8;                // 0..2040
        const float* g = wr + (2040 - t8);
        float4 lo = *(const float4*)g;
        float4 hi = *(const float4*)(g + 4);
        uint4 v;
        v.x = f2bf(hi.w) | (f2bf(hi.z) << 16);
        v.y = f2bf(hi.y) | (f2bf(hi.x) << 16);
        v.z = f2bf(lo.w) | (f2bf(lo.z) << 16);
        v.w = f2bf(lo.y) | (f2bf(lo.x) << 16);
        *(uint4*)(smem + 8 + t8) = v;
        if (tid < 21) {                        // guard (8) + pad (160)
            uint4 z = {0u, 0u, 0u, 0u};
            unsigned short* dst = (tid == 0) ? smem
                                 : smem + 8 + 2048 + (tid - 1) * 8;
            *(uint4*)dst = z;
        }
    }
    __syncthreads();

    // ---- phase 2: 8 shifted copies, vectorized: copy_c[i] = wbase[i-c] ----
    #pragma unroll
    for (int c = 0; c < 8; ++c) {
        for (int grp = tid; grp < WSTRIDE / 8; grp += NTH) {
            const int i = grp * 8;
            uint4 g0 = *(const uint4*)(smem + 8 + i - 8);
            uint4 g1 = *(const uint4*)(smem + 8 + i);
            unsigned d[9] = {g0.x, g0.y, g0.z, g0.w,
                             g1.x, g1.y, g1.z, g1.w, 0u};
            const int qd = (16 - 2 * c) >> 2;
            uint4 o;
            if (c & 1) {
                o.x = (d[qd]     >> 16) | (d[qd + 1] << 16);
                o.y = (d[qd + 1] >> 16) | (d[qd + 2] << 16);
                o.z = (d[qd + 2] >> 16) | (d[qd + 3] << 16);
                o.w = (d[qd + 3] >> 16) | (d[qd + 4] << 16);
            } else {
                o.x = d[qd];     o.y = d[qd + 1];
                o.z = d[qd + 2]; o.w = d[qd + 3];
            }
            *(uint4*)(wc + c * WSTRIDE + i) = o;
        }
    }
    __syncthreads();
    // LAST barrier in the kernel: wcop read-only, A slices wave-private.

    // ---- per-lane MFMA constants ----
    const int col_low = lane & 15;
    const int kq      = lane >> 4;
    const int kq16    = kq * 16;
    const int cpy     = (col_low + 1) & 7;     // alignment class -> copy id
    const int BcBase  = cpy * WSTRIDE + cpy + 2047 - col_low + 8 * kq;
    const int Arow0   = (rbw + col_low) * 64;
    const int Arow1   = Arow0 + 1024;

    // ---- two col tiles per block: ct_hi then ct_lo (68 chunks total) ----
    for (int half = 0; half < 2; ++half) {
        const int ct  = half ? ct_lo : ct_hi;
        const int t0  = ct << 7;
        const int nch = 4 * (ct + 1);          // K chunks of 32
        const unsigned short* wp = wc + (BcBase - t0);
        const float* Xt = Xp;

        if (half) { LOADPF(pf0, 0); LOADPF(pf1, 32); }
        WRITEA(ab0, pf0);                      // seed chunk 0
        LOADPF(pf0, 64);                       // pf0 <- chunk 2 (nch >= 4)

        // circular B window init: slots for chunk 0 (words n = -7..0)
        bf16x8 bwc[8];
        bwc[0] = *(const bf16x8*)(wp);
        bwc[7] = *(const bf16x8*)(wp - 16);
        bwc[6] = *(const bf16x8*)(wp - 32);
        bwc[5] = *(const bf16x8*)(wp - 48);
        bwc[4] = *(const bf16x8*)(wp - 64);
        bwc[3] = *(const bf16x8*)(wp - 80);
        bwc[2] = *(const bf16x8*)(wp - 96);
        bwc[1] = *(const bf16x8*)(wp - 112);

        f32x4 acc[2][8] = {};
        const int nt1 = (nch >> 2) - 1;        // full iterations before tail
        for (int t = 0; t < nt1; ++t) {
            CHUNK32(0, ab0, ab1, pf1, 0);
            CHUNK32(1, ab1, ab0, pf0, 0);
            CHUNK32(2, ab0, ab1, pf1, 0);
            CHUNK32(3, ab1, ab0, pf0, 0);
            Xt += 4 * BK;
            wp += 4 * BK;
        }
        // tail iteration (guards strip trailing prefetch/stage/refill)
        CHUNK32(0, ab0, ab1, pf1, 1);
        CHUNK32(1, ab1, ab0, pf0, 1);
        CHUNK32(2, ab0, ab1, pf1, 1);
        CHUNK32(3, ab1, ab0, pf0, 1);

        // epilogue: C/D layout col=lane&15, row=(lane>>4)*4+reg
        #pragma unroll
        for (int c = 0; c < 8; ++c) {
            const int colg = t0 + 16 * c + col_low;
            const float bv = br[colg];
            #pragma unroll
            for (int a = 0; a < 2; ++a) {
                const int rowl = rbw + 16 * a + 4 * kq;
                #pragma unroll
                for (int r = 0; r < 4; ++r)
                    Ob[(size_t)(rowl + r) * SEQ + colg] = acc[a][c][r] + bv;
            }
        }
    }
}

extern "C" void kernel_launch(void* const* d_in, const int* in_sizes, int n_in,
                              void* d_out, int out_size, void* d_ws, size_t ws_size,
                              hipStream_t stream) {
    const float* x  = (const float*)d_in[0];
    const float* w  = (const float*)d_in[1];
    const float* bs = (const float*)d_in[2];
    float* out = (float*)d_out;
    dim3 grid(512);    // 16 heads x 4 row tiles x 8 uniform ct-pairs
    dim3 block(NTH);
    hipLaunchKernelGGL(mixer_kernel, grid, block, 0, stream, x, w, bs, out);
}